// Round 10
// baseline (404.575 us; speedup 1.0000x reference)
//
#include <hip/hip_runtime.h>
#include <math.h>

typedef __bf16 bf16x8 __attribute__((ext_vector_type(8)));
typedef _Float16 f16x8 __attribute__((ext_vector_type(8)));
typedef float f32x4 __attribute__((ext_vector_type(4)));

__device__ __forceinline__ unsigned short f2bf(float f) {
  unsigned int u = __builtin_bit_cast(unsigned int, f);
  u += 0x7fffu + ((u >> 16) & 1u);
  return (unsigned short)(u >> 16);
}
__device__ __forceinline__ unsigned int pack2bf(float a, float b) {
  return (unsigned int)f2bf(a) | ((unsigned int)f2bf(b) << 16);
}

// ---------- bf16 MFMA GEMM + sigmoid + avgpool2 (fp32->bf16 staged inline) ----------
#define GK_PADK 40
template <int WFP32, int XFP32>
__global__ __launch_bounds__(256) void gemm_mfma_sig_pool(
    const void* __restrict__ Wv, const float* __restrict__ bias,
    const void* __restrict__ Xv, void* __restrict__ Y,
    int K, int Np, int out_bf16) {
  __shared__ unsigned short Wt[64][GK_PADK];
  __shared__ unsigned short Xt[64][GK_PADK];
  const int tid = threadIdx.x;
  const int i_base = blockIdx.x * 64;
  const int b_base = blockIdx.y * 64;
  const int srow = tid >> 2, sseg = tid & 3;
  const int wv = tid >> 6, lane = tid & 63;
  const int wn = wv & 1, wb = wv >> 1;
  const int L15 = lane & 15, q = lane >> 4;

  f32x4 acc[2][2] = {};
  for (int k0 = 0; k0 < K; k0 += 32) {
    if (WFP32) {
      const float* Wf = (const float*)Wv;
      const float4 a = *(const float4*)&Wf[(size_t)(i_base + srow) * K + k0 + sseg * 8];
      const float4 b = *(const float4*)&Wf[(size_t)(i_base + srow) * K + k0 + sseg * 8 + 4];
      uint4 p = { pack2bf(a.x, a.y), pack2bf(a.z, a.w), pack2bf(b.x, b.y), pack2bf(b.z, b.w) };
      *(uint4*)&Wt[srow][sseg * 8] = p;
    } else {
      *(uint4*)&Wt[srow][sseg * 8] =
          *(const uint4*)&((const unsigned short*)Wv)[(size_t)(i_base + srow) * K + k0 + sseg * 8];
    }
    if (XFP32) {
      const float* Xf = (const float*)Xv;
      const float4 a = *(const float4*)&Xf[(size_t)(b_base + srow) * K + k0 + sseg * 8];
      const float4 b = *(const float4*)&Xf[(size_t)(b_base + srow) * K + k0 + sseg * 8 + 4];
      uint4 p = { pack2bf(a.x, a.y), pack2bf(a.z, a.w), pack2bf(b.x, b.y), pack2bf(b.z, b.w) };
      *(uint4*)&Xt[srow][sseg * 8] = p;
    } else {
      *(uint4*)&Xt[srow][sseg * 8] =
          *(const uint4*)&((const unsigned short*)Xv)[(size_t)(b_base + srow) * K + k0 + sseg * 8];
    }
    __syncthreads();
    bf16x8 a0 = *(const bf16x8*)&Wt[wn * 32 + L15][q * 8];
    bf16x8 a1 = *(const bf16x8*)&Wt[wn * 32 + 16 + L15][q * 8];
    bf16x8 b0 = *(const bf16x8*)&Xt[wb * 32 + L15][q * 8];
    bf16x8 b1 = *(const bf16x8*)&Xt[wb * 32 + 16 + L15][q * 8];
    acc[0][0] = __builtin_amdgcn_mfma_f32_16x16x32_bf16(a0, b0, acc[0][0], 0, 0, 0);
    acc[0][1] = __builtin_amdgcn_mfma_f32_16x16x32_bf16(a0, b1, acc[0][1], 0, 0, 0);
    acc[1][0] = __builtin_amdgcn_mfma_f32_16x16x32_bf16(a1, b0, acc[1][0], 0, 0, 0);
    acc[1][1] = __builtin_amdgcn_mfma_f32_16x16x32_bf16(a1, b1, acc[1][1], 0, 0, 0);
    __syncthreads();
  }

  const int nb0 = i_base + wn * 32;
  const int bc0 = b_base + wb * 32 + L15;
#pragma unroll
  for (int mg = 0; mg < 2; mg++) {
    const int nrow = nb0 + mg * 16 + q * 4;
    const float bi0 = bias[nrow], bi1 = bias[nrow + 1];
    const float bi2 = bias[nrow + 2], bi3 = bias[nrow + 3];
#pragma unroll
    for (int bg = 0; bg < 2; bg++) {
      const int b = bc0 + bg * 16;
      f32x4 A = acc[mg][bg];
      const float a0 = __builtin_amdgcn_rcpf(1.f + __expf(-(A[0] + bi0)));
      const float a1 = __builtin_amdgcn_rcpf(1.f + __expf(-(A[1] + bi1)));
      const float a2 = __builtin_amdgcn_rcpf(1.f + __expf(-(A[2] + bi2)));
      const float a3 = __builtin_amdgcn_rcpf(1.f + __expf(-(A[3] + bi3)));
      const float p0 = 0.5f * (a0 + a1), p1 = 0.5f * (a2 + a3);
      const int pidx = nrow >> 1;  // even
      if (out_bf16) {
        *(unsigned int*)&((unsigned short*)Y)[(size_t)b * Np + pidx] = pack2bf(p0, p1);
      } else {
        *(float2*)&((float*)Y)[(size_t)b * Np + pidx] = make_float2(p0, p1);
      }
    }
  }
}

// ---------- MFMA LSTM tail ----------
// 32 WGs x 8 batches, 448 thr (7 waves). Wave w owns hid block [16w,16w+16);
// its 4 N-tiles are gates i,f,g,o of that block, so after the K-loop each
// lane holds all 4 gates for 4 batch rows of 1 hid -> c/h update is fully
// in-lane (no gate exchange). Weights are fp16 MFMA B-fragments: MFMA reads
// A/B from AGPRs natively, so even if RA banishes them to AGPRs (the R3-R9
// failure mode: 64-VGPR cap + accvgpr shuttling) they are consumed in place.
// h is fp32 in the cell update, quantized to fp16 only for the matmul
// (fp16 mantissa 10 bits -> ~5e-4 rel, vs bf16 4e-3). One barrier per step.
#define HID 100
#define TSTEPS 256
#define BPG 8
#define HROW 152  // fp16 elems per h row: 304 B, 16B-aligned, banks 12/row -> <=2-way

__global__ __launch_bounds__(448) __attribute__((amdgpu_waves_per_eu(1, 2)))
void lstm_tail_mfma(
    const float* __restrict__ X, const float* __restrict__ Wih,
    const float* __restrict__ Whh, const float* __restrict__ bgates,
    const float* __restrict__ Wout, const float* __restrict__ bout,
    float* __restrict__ out) {
  const int bat0 = blockIdx.x * BPG;
  const int t = threadIdx.x;
  const int w = t >> 6;       // wave -> hid block
  const int l = t & 63;
  const int quad = l >> 4;
  const int c = l & 15;
  const int hid = 16 * w + c;
  const bool hvalid = (hid < HID);
  const int hid0 = hvalid ? hid : 0;
  const bool bvalid = (quad < 2);
  const bool wr = hvalid && bvalid;

  __shared__ _Float16 hbuf[2][16][HROW];
  __shared__ float xr[BPG][TSTEPS];
  __shared__ float red[256];

  for (int i = t; i < 2 * 16 * HROW; i += 448) ((_Float16*)hbuf)[i] = (_Float16)0.f;
  for (int i = t; i < BPG * TSTEPS; i += 448) {
    const int b = i >> 8, tt = i & 255;
    xr[b][tt] = X[(size_t)(bat0 + b) * TSTEPS + tt];
  }

  // 16 fp16 B-fragments: (gate J, k-tile KT); zero-padded for k>=100 / hid>=100
#define LOADW(J, KT, DST) { f16x8 tmp; _Pragma("unroll") \
    for (int m = 0; m < 8; m++) { \
      const int k = (KT) * 32 + quad * 8 + m; \
      const float v = (hvalid && k < HID) ? Whh[(size_t)((J) * HID + hid0) * HID + k] : 0.f; \
      tmp[m] = (_Float16)v; } DST = tmp; }
  f16x8 w00, w01, w02, w03, w10, w11, w12, w13;
  f16x8 w20, w21, w22, w23, w30, w31, w32, w33;
  LOADW(0, 0, w00) LOADW(0, 1, w01) LOADW(0, 2, w02) LOADW(0, 3, w03)
  LOADW(1, 0, w10) LOADW(1, 1, w11) LOADW(1, 2, w12) LOADW(1, 3, w13)
  LOADW(2, 0, w20) LOADW(2, 1, w21) LOADW(2, 2, w22) LOADW(2, 3, w23)
  LOADW(3, 0, w30) LOADW(3, 1, w31) LOADW(3, 2, w32) LOADW(3, 3, w33)
#undef LOADW

  const float u0 = hvalid ? Wih[0 * HID + hid0] : 0.f;
  const float u1 = hvalid ? Wih[1 * HID + hid0] : 0.f;
  const float u2 = hvalid ? Wih[2 * HID + hid0] : 0.f;
  const float u3 = hvalid ? Wih[3 * HID + hid0] : 0.f;
  const float bz0 = hvalid ? bgates[0 * HID + hid0] : 0.f;
  const float bz1 = hvalid ? bgates[1 * HID + hid0] : 0.f;
  const float bz2 = hvalid ? bgates[2 * HID + hid0] : 0.f;
  const float bz3 = hvalid ? bgates[3 * HID + hid0] : 0.f;

  float c0 = 0.f, c1 = 0.f, c2 = 0.f, c3 = 0.f;
  __syncthreads();

#define SIG(zz) __builtin_amdgcn_rcpf(1.f + __expf(-(zz)))
  for (int step = 0; step < TSTEPS; step++) {
    const int cur = step & 1, nxt = cur ^ 1;
    // A-fragments: batch row = lane&15, k = quad*8+j (per K-tile)
    const f16x8 a0 = *(const f16x8*)&hbuf[cur][c][0 * 32 + quad * 8];
    const f16x8 a1 = *(const f16x8*)&hbuf[cur][c][1 * 32 + quad * 8];
    const f16x8 a2 = *(const f16x8*)&hbuf[cur][c][2 * 32 + quad * 8];
    const f16x8 a3 = *(const f16x8*)&hbuf[cur][c][3 * 32 + quad * 8];
    f32x4 z0 = {0.f, 0.f, 0.f, 0.f}, z1 = z0, z2 = z0, z3 = z0;
    z0 = __builtin_amdgcn_mfma_f32_16x16x32_f16(a0, w00, z0, 0, 0, 0);
    z1 = __builtin_amdgcn_mfma_f32_16x16x32_f16(a0, w10, z1, 0, 0, 0);
    z2 = __builtin_amdgcn_mfma_f32_16x16x32_f16(a0, w20, z2, 0, 0, 0);
    z3 = __builtin_amdgcn_mfma_f32_16x16x32_f16(a0, w30, z3, 0, 0, 0);
    z0 = __builtin_amdgcn_mfma_f32_16x16x32_f16(a1, w01, z0, 0, 0, 0);
    z1 = __builtin_amdgcn_mfma_f32_16x16x32_f16(a1, w11, z1, 0, 0, 0);
    z2 = __builtin_amdgcn_mfma_f32_16x16x32_f16(a1, w21, z2, 0, 0, 0);
    z3 = __builtin_amdgcn_mfma_f32_16x16x32_f16(a1, w31, z3, 0, 0, 0);
    z0 = __builtin_amdgcn_mfma_f32_16x16x32_f16(a2, w02, z0, 0, 0, 0);
    z1 = __builtin_amdgcn_mfma_f32_16x16x32_f16(a2, w12, z1, 0, 0, 0);
    z2 = __builtin_amdgcn_mfma_f32_16x16x32_f16(a2, w22, z2, 0, 0, 0);
    z3 = __builtin_amdgcn_mfma_f32_16x16x32_f16(a2, w32, z3, 0, 0, 0);
    z0 = __builtin_amdgcn_mfma_f32_16x16x32_f16(a3, w03, z0, 0, 0, 0);
    z1 = __builtin_amdgcn_mfma_f32_16x16x32_f16(a3, w13, z1, 0, 0, 0);
    z2 = __builtin_amdgcn_mfma_f32_16x16x32_f16(a3, w23, z2, 0, 0, 0);
    z3 = __builtin_amdgcn_mfma_f32_16x16x32_f16(a3, w33, z3, 0, 0, 0);

    const int xb = (quad & 1) * 4;  // batch rows for this lane's acc (valid quads 0,1)
    const float x0 = xr[xb + 0][step], x1 = xr[xb + 1][step];
    const float x2 = xr[xb + 2][step], x3 = xr[xb + 3][step];

#define STEPR(R, XV, CC) { \
      const float zi = z0[R] + fmaf(u0, XV, bz0); \
      const float zf = z1[R] + fmaf(u1, XV, bz1); \
      const float zg = z2[R] + fmaf(u2, XV, bz2); \
      const float zo = z3[R] + fmaf(u3, XV, bz3); \
      const float ai = SIG(zi), af = SIG(zf), ao = SIG(zo); \
      const float ag = 2.f * SIG(2.f * zg) - 1.f; \
      CC = fmaf(af, CC, ai * ag); \
      const float th = 2.f * SIG(2.f * CC) - 1.f; \
      if (wr) hbuf[nxt][quad * 4 + R][hid] = (_Float16)(ao * th); }
    STEPR(0, x0, c0)
    STEPR(1, x1, c1)
    STEPR(2, x2, c2)
    STEPR(3, x3, c3)
#undef STEPR
    __syncthreads();
  }
#undef SIG

  // out[b] = dot(h_final, Wout) + bout ; h_final in hbuf[0] (256 steps even)
  if (t < 256) {
    const int b = t >> 5, s = t & 31;
    float acc = 0.f;
    for (int hh = s; hh < HID; hh += 32)
      acc = fmaf((float)hbuf[0][b][hh], Wout[hh], acc);
    red[t] = acc;
  }
  __syncthreads();
  if (t < BPG) {
    float ssum = 0.f;
#pragma unroll
    for (int s = 0; s < 32; s++) ssum += red[t * 32 + s];
    out[bat0 + t] = ssum + bout[0];
  }
}

// ---------- launch ----------
extern "C" void kernel_launch(void* const* d_in, const int* in_sizes, int n_in,
                              void* d_out, int out_size, void* d_ws, size_t ws_size,
                              hipStream_t stream) {
  const float* x    = (const float*)d_in[0];   // (256,1024)
  const float* W1L  = (const float*)d_in[3];   // (1024,1024)
  const float* b1L  = (const float*)d_in[4];
  const float* W2L  = (const float*)d_in[7];   // (512,512)
  const float* b2L  = (const float*)d_in[8];
  const float* Wih3 = (const float*)d_in[15];  // (400,1)
  const float* Whh3 = (const float*)d_in[16];  // (400,100)
  const float* b3   = (const float*)d_in[17];  // (400,)
  const float* Wout = (const float*)d_in[18];  // (1,100)
  const float* bout = (const float*)d_in[19];  // (1,)
  float* out = (float*)d_out;                  // (256,)

  unsigned short* xl1b = (unsigned short*)d_ws;     // 256x512 bf16
  float* xl2 = (float*)(xl1b + (size_t)256 * 512);  // 256x256 f32

  gemm_mfma_sig_pool<1, 1><<<dim3(16, 4), 256, 0, stream>>>(W1L, b1L, x, xl1b, 1024, 512, 1);
  gemm_mfma_sig_pool<1, 0><<<dim3(8, 4), 256, 0, stream>>>(W2L, b2L, xl1b, xl2, 512, 256, 0);
  lstm_tail_mfma<<<32, 448, 0, stream>>>(xl2, Wih3, Whh3, b3, Wout, bout, out);
}

// Round 11
// 274.114 us; speedup vs baseline: 1.4759x; 1.4759x over previous
//
#include <hip/hip_runtime.h>
#include <math.h>

typedef __bf16 bf16x8 __attribute__((ext_vector_type(8)));
typedef float f32x4 __attribute__((ext_vector_type(4)));

__device__ __forceinline__ unsigned short f2bf(float f) {
  unsigned int u = __builtin_bit_cast(unsigned int, f);
  u += 0x7fffu + ((u >> 16) & 1u);
  return (unsigned short)(u >> 16);
}
__device__ __forceinline__ unsigned int pack2bf(float a, float b) {
  return (unsigned int)f2bf(a) | ((unsigned int)f2bf(b) << 16);
}

// ---------- bf16 MFMA GEMM + sigmoid + avgpool2 (fp32->bf16 staged inline) ----------
#define GK_PADK 40
template <int WFP32, int XFP32>
__global__ __launch_bounds__(256) void gemm_mfma_sig_pool(
    const void* __restrict__ Wv, const float* __restrict__ bias,
    const void* __restrict__ Xv, void* __restrict__ Y,
    int K, int Np, int out_bf16) {
  __shared__ unsigned short Wt[64][GK_PADK];
  __shared__ unsigned short Xt[64][GK_PADK];
  const int tid = threadIdx.x;
  const int i_base = blockIdx.x * 64;
  const int b_base = blockIdx.y * 64;
  const int srow = tid >> 2, sseg = tid & 3;
  const int wv = tid >> 6, lane = tid & 63;
  const int wn = wv & 1, wb = wv >> 1;
  const int L15 = lane & 15, q = lane >> 4;

  f32x4 acc[2][2] = {};
  for (int k0 = 0; k0 < K; k0 += 32) {
    if (WFP32) {
      const float* Wf = (const float*)Wv;
      const float4 a = *(const float4*)&Wf[(size_t)(i_base + srow) * K + k0 + sseg * 8];
      const float4 b = *(const float4*)&Wf[(size_t)(i_base + srow) * K + k0 + sseg * 8 + 4];
      uint4 p = { pack2bf(a.x, a.y), pack2bf(a.z, a.w), pack2bf(b.x, b.y), pack2bf(b.z, b.w) };
      *(uint4*)&Wt[srow][sseg * 8] = p;
    } else {
      *(uint4*)&Wt[srow][sseg * 8] =
          *(const uint4*)&((const unsigned short*)Wv)[(size_t)(i_base + srow) * K + k0 + sseg * 8];
    }
    if (XFP32) {
      const float* Xf = (const float*)Xv;
      const float4 a = *(const float4*)&Xf[(size_t)(b_base + srow) * K + k0 + sseg * 8];
      const float4 b = *(const float4*)&Xf[(size_t)(b_base + srow) * K + k0 + sseg * 8 + 4];
      uint4 p = { pack2bf(a.x, a.y), pack2bf(a.z, a.w), pack2bf(b.x, b.y), pack2bf(b.z, b.w) };
      *(uint4*)&Xt[srow][sseg * 8] = p;
    } else {
      *(uint4*)&Xt[srow][sseg * 8] =
          *(const uint4*)&((const unsigned short*)Xv)[(size_t)(b_base + srow) * K + k0 + sseg * 8];
    }
    __syncthreads();
    bf16x8 a0 = *(const bf16x8*)&Wt[wn * 32 + L15][q * 8];
    bf16x8 a1 = *(const bf16x8*)&Wt[wn * 32 + 16 + L15][q * 8];
    bf16x8 b0 = *(const bf16x8*)&Xt[wb * 32 + L15][q * 8];
    bf16x8 b1 = *(const bf16x8*)&Xt[wb * 32 + 16 + L15][q * 8];
    acc[0][0] = __builtin_amdgcn_mfma_f32_16x16x32_bf16(a0, b0, acc[0][0], 0, 0, 0);
    acc[0][1] = __builtin_amdgcn_mfma_f32_16x16x32_bf16(a0, b1, acc[0][1], 0, 0, 0);
    acc[1][0] = __builtin_amdgcn_mfma_f32_16x16x32_bf16(a1, b0, acc[1][0], 0, 0, 0);
    acc[1][1] = __builtin_amdgcn_mfma_f32_16x16x32_bf16(a1, b1, acc[1][1], 0, 0, 0);
    __syncthreads();
  }

  const int nb0 = i_base + wn * 32;
  const int bc0 = b_base + wb * 32 + L15;
#pragma unroll
  for (int mg = 0; mg < 2; mg++) {
    const int nrow = nb0 + mg * 16 + q * 4;
    const float bi0 = bias[nrow], bi1 = bias[nrow + 1];
    const float bi2 = bias[nrow + 2], bi3 = bias[nrow + 3];
#pragma unroll
    for (int bg = 0; bg < 2; bg++) {
      const int b = bc0 + bg * 16;
      f32x4 A = acc[mg][bg];
      const float a0 = __builtin_amdgcn_rcpf(1.f + __expf(-(A[0] + bi0)));
      const float a1 = __builtin_amdgcn_rcpf(1.f + __expf(-(A[1] + bi1)));
      const float a2 = __builtin_amdgcn_rcpf(1.f + __expf(-(A[2] + bi2)));
      const float a3 = __builtin_amdgcn_rcpf(1.f + __expf(-(A[3] + bi3)));
      const float p0 = 0.5f * (a0 + a1), p1 = 0.5f * (a2 + a3);
      const int pidx = nrow >> 1;  // even
      if (out_bf16) {
        *(unsigned int*)&((unsigned short*)Y)[(size_t)b * Np + pidx] = pack2bf(p0, p1);
      } else {
        *(float2*)&((float*)Y)[(size_t)b * Np + pidx] = make_float2(p0, p1);
      }
    }
  }
}

// ---------- LSTM tail ----------
// Lane (r=t>>2, kq=t&3) owns all 4 gates of hidden row r over k-quarter
// [25kq, 25kq+25) -> 100 fp32 weights/lane, as named SSA values (no alloca;
// fixes the R1/R2 SROA->scratch failure) + ONE 28-operand asm touch per
// iteration (forces all 100 simultaneously live). NEW vs R9: the register
// budget itself. R3-R9 relied on the amdgpu_waves_per_eu attribute (never
// moved VGPR_Count off 64 -> evidently ignored); R1/R2 had the documented
// HIP knob __launch_bounds__(448, 1) (min-waves/EU=1 -> 512-reg budget) but
// array weights. This round combines launch_bounds(448,1) + SSA + mega-asm
// for the first time. h in LDS at stride 36 (conflict-free, validated R6).
// Quad butterfly (DPP 0xB1+0x4E) completes the dots; one barrier per step.
#define HID 100
#define TSTEPS 256
#define HSTRIDE 36

__device__ __forceinline__ float qx1(float x) {
  int v = __builtin_amdgcn_mov_dpp(__builtin_bit_cast(int, x), 0xB1, 0xf, 0xf, true);
  return x + __builtin_bit_cast(float, v);
}
__device__ __forceinline__ float qx2(float x) {
  int v = __builtin_amdgcn_mov_dpp(__builtin_bit_cast(int, x), 0x4E, 0xf, 0xf, true);
  return x + __builtin_bit_cast(float, v);
}

__global__ __launch_bounds__(448, 1) void lstm_tail(
    const float* __restrict__ X, const float* __restrict__ Wih,
    const float* __restrict__ Whh, const float* __restrict__ bgates,
    const float* __restrict__ Wout, const float* __restrict__ bout,
    float* __restrict__ out) {
  const int bat = blockIdx.x;
  const int t = threadIdx.x;
  const int r = t >> 2;        // hidden row (valid < 100)
  const int kq = t & 3;        // k quarter
  const int koff = 25 * kq;
  const bool valid = (r < HID);
  const int rr = valid ? r : 0;
  __shared__ __align__(16) float hbuf[2][160];
  __shared__ float xrow[TSTEPS];
  __shared__ float red[HID];

  for (int i = t; i < TSTEPS; i += 448) xrow[i] = X[(size_t)bat * TSTEPS + i];

  const float* Wr0 = &Whh[(size_t)(0 * HID + rr) * HID + koff];
  const float* Wr1 = &Whh[(size_t)(1 * HID + rr) * HID + koff];
  const float* Wr2 = &Whh[(size_t)(2 * HID + rr) * HID + koff];
  const float* Wr3 = &Whh[(size_t)(3 * HID + rr) * HID + koff];

#define DECLW(P) f32x4 P##_0, P##_1, P##_2, P##_3, P##_4, P##_5; float P##_6;
  DECLW(wi) DECLW(wf) DECLW(wg) DECLW(wo)
#undef DECLW
#define LW(P, B)                                               \
  P##_0 = (f32x4){B[0],  B[1],  B[2],  B[3]};                  \
  P##_1 = (f32x4){B[4],  B[5],  B[6],  B[7]};                  \
  P##_2 = (f32x4){B[8],  B[9],  B[10], B[11]};                 \
  P##_3 = (f32x4){B[12], B[13], B[14], B[15]};                 \
  P##_4 = (f32x4){B[16], B[17], B[18], B[19]};                 \
  P##_5 = (f32x4){B[20], B[21], B[22], B[23]};                 \
  P##_6 = B[24];
  LW(wi, Wr0) LW(wf, Wr1) LW(wg, Wr2) LW(wo, Wr3)
#undef LW

  const float bi_ = bgates[0 * HID + rr], bf_ = bgates[1 * HID + rr];
  const float bg_ = bgates[2 * HID + rr], bo_ = bgates[3 * HID + rr];
  const float ui = Wih[0 * HID + rr], uf = Wih[1 * HID + rr];
  const float ug = Wih[2 * HID + rr], uo = Wih[3 * HID + rr];

  const int hpos = (rr / 25) * HSTRIDE + (rr % 25);  // conflict-free chunk slot

  if (t < 160) { hbuf[0][t] = 0.f; hbuf[1][t] = 0.f; }
  float c = 0.f;
  __syncthreads();

  for (int step = 0; step < TSTEPS; step++) {
    // Single opaque touch of ALL 100 weight floats: forces simultaneous
    // liveness each iteration so RA must allocate real registers (budget now
    // 512 via __launch_bounds__(448, 1) min-waves/EU = 1).
    asm volatile(""
        : "+v"(wi_0), "+v"(wi_1), "+v"(wi_2), "+v"(wi_3), "+v"(wi_4), "+v"(wi_5), "+v"(wi_6),
          "+v"(wf_0), "+v"(wf_1), "+v"(wf_2), "+v"(wf_3), "+v"(wf_4), "+v"(wf_5), "+v"(wf_6),
          "+v"(wg_0), "+v"(wg_1), "+v"(wg_2), "+v"(wg_3), "+v"(wg_4), "+v"(wg_5), "+v"(wg_6),
          "+v"(wo_0), "+v"(wo_1), "+v"(wo_2), "+v"(wo_3), "+v"(wo_4), "+v"(wo_5), "+v"(wo_6));
    const float* hq = &hbuf[step & 1][kq * HSTRIDE];
    float z0 = 0.f, z1 = 0.f, z2 = 0.f, z3 = 0.f;
#define G4(OFF, WI, WF, WG, WO)                                                  \
    { const float4 h4 = *(const float4*)&hq[OFF];                                \
      z0 = fmaf(WI[0], h4.x, z0); z1 = fmaf(WF[0], h4.x, z1);                    \
      z2 = fmaf(WG[0], h4.x, z2); z3 = fmaf(WO[0], h4.x, z3);                    \
      z0 = fmaf(WI[1], h4.y, z0); z1 = fmaf(WF[1], h4.y, z1);                    \
      z2 = fmaf(WG[1], h4.y, z2); z3 = fmaf(WO[1], h4.y, z3);                    \
      z0 = fmaf(WI[2], h4.z, z0); z1 = fmaf(WF[2], h4.z, z1);                    \
      z2 = fmaf(WG[2], h4.z, z2); z3 = fmaf(WO[2], h4.z, z3);                    \
      z0 = fmaf(WI[3], h4.w, z0); z1 = fmaf(WF[3], h4.w, z1);                    \
      z2 = fmaf(WG[3], h4.w, z2); z3 = fmaf(WO[3], h4.w, z3); }
    G4(0,  wi_0, wf_0, wg_0, wo_0)
    G4(4,  wi_1, wf_1, wg_1, wo_1)
    G4(8,  wi_2, wf_2, wg_2, wo_2)
    G4(12, wi_3, wf_3, wg_3, wo_3)
    G4(16, wi_4, wf_4, wg_4, wo_4)
    G4(20, wi_5, wf_5, wg_5, wo_5)
    { const float h1 = hq[24];
      z0 = fmaf(wi_6, h1, z0); z1 = fmaf(wf_6, h1, z1);
      z2 = fmaf(wg_6, h1, z2); z3 = fmaf(wo_6, h1, z3); }
#undef G4
    // quad butterfly: every lane of the quad gets the full 100-k sums
    z0 = qx2(qx1(z0)); z1 = qx2(qx1(z1)); z2 = qx2(qx1(z2)); z3 = qx2(qx1(z3));

    const float xt = xrow[step];
    const float zi = fmaf(ui, xt, z0 + bi_);
    const float zf = fmaf(uf, xt, z1 + bf_);
    const float zg = fmaf(ug, xt, z2 + bg_);
    const float zo = fmaf(uo, xt, z3 + bo_);
    const float ai = __builtin_amdgcn_rcpf(1.f + __expf(-zi));
    const float af = __builtin_amdgcn_rcpf(1.f + __expf(-zf));
    const float ag = 2.f * __builtin_amdgcn_rcpf(1.f + __expf(-2.f * zg)) - 1.f;
    const float ao = __builtin_amdgcn_rcpf(1.f + __expf(-zo));
    c = fmaf(af, c, ai * ag);
    const float th = 2.f * __builtin_amdgcn_rcpf(1.f + __expf(-2.f * c)) - 1.f;
    if (kq == 0 && valid) hbuf[(step & 1) ^ 1][hpos] = ao * th;
    __syncthreads();
  }

  if (t < HID) red[t] = hbuf[0][(t / 25) * HSTRIDE + (t % 25)] * Wout[t];
  __syncthreads();
  if (t == 0) {
    float s = 0.f;
#pragma unroll
    for (int k = 0; k < HID; k++) s += red[k];
    out[bat] = s + bout[0];
  }
}

// ---------- launch ----------
extern "C" void kernel_launch(void* const* d_in, const int* in_sizes, int n_in,
                              void* d_out, int out_size, void* d_ws, size_t ws_size,
                              hipStream_t stream) {
  const float* x    = (const float*)d_in[0];   // (256,1024)
  const float* W1L  = (const float*)d_in[3];   // (1024,1024)
  const float* b1L  = (const float*)d_in[4];
  const float* W2L  = (const float*)d_in[7];   // (512,512)
  const float* b2L  = (const float*)d_in[8];
  const float* Wih3 = (const float*)d_in[15];  // (400,1)
  const float* Whh3 = (const float*)d_in[16];  // (400,100)
  const float* b3   = (const float*)d_in[17];  // (400,)
  const float* Wout = (const float*)d_in[18];  // (1,100)
  const float* bout = (const float*)d_in[19];  // (1,)
  float* out = (float*)d_out;                  // (256,)

  unsigned short* xl1b = (unsigned short*)d_ws;     // 256x512 bf16
  float* xl2 = (float*)(xl1b + (size_t)256 * 512);  // 256x256 f32

  gemm_mfma_sig_pool<1, 1><<<dim3(16, 4), 256, 0, stream>>>(W1L, b1L, x, xl1b, 1024, 512, 1);
  gemm_mfma_sig_pool<1, 0><<<dim3(8, 4), 256, 0, stream>>>(W2L, b2L, xl1b, xl2, 512, 256, 0);
  lstm_tail<<<256, 448, 0, stream>>>(xl2, Wih3, Whh3, b3, Wout, bout, out);
}